// Round 8
// baseline (338.319 us; speedup 1.0000x reference)
//
#include <hip/hip_runtime.h>
#include <hip/hip_bf16.h>

#define HW 131072      // h*w
#define NCH 128        // channels
#define KS 9
#define L_TOTAL 163840 // Q*M*M
#define LPW 16         // l's per wave in main kernel

typedef float        f32x2 __attribute__((ext_vector_type(2)));
typedef unsigned int u32x2 __attribute__((ext_vector_type(2)));

static __device__ __forceinline__ float bflo(unsigned int p) { return __uint_as_float(p << 16); }
static __device__ __forceinline__ float bfhi(unsigned int p) { return __uint_as_float(p & 0xffff0000u); }
static __device__ __forceinline__ unsigned short f2bf(float f) {
    unsigned int x = __float_as_uint(f);
    return (unsigned short)((x + 0x7fffu + ((x >> 16) & 1u)) >> 16);  // RNE
}
static __device__ __forceinline__ unsigned int pack2(float a, float b) {
    return (unsigned int)f2bf(a) | ((unsigned int)f2bf(b) << 16);
}

// ---------------------------------------------------------------------------
// Kernel A: transpose x[c][p] (fp32) -> xT[p][c] (bf16 pairs) AND per-p
// channel mean/max. x read nt (read-once).
// Grid: HW/128 = 1024 blocks, 256 threads.
// ---------------------------------------------------------------------------
__global__ __launch_bounds__(256) void transpose_x_kernel(
    const f32x2* __restrict__ xf,         // x: [NCH][HW/2] float2 along p
    unsigned int* __restrict__ xT,        // [HW][NCH/2] uint pairs along c
    float2* __restrict__ meanmaxP)        // [HW] (mean, max) over channels
{
    __shared__ unsigned short tile[128 * 128];  // [p][col'], rotate swizzle
    __shared__ float ps[4][128];
    __shared__ float pm[4][128];
    const int tid = threadIdx.x;
    const int lane = tid & 63;
    const int wave = tid >> 6;
    const int p0 = blockIdx.x * 128;
    const int pa = 2 * lane, pb = 2 * lane + 1;

    float s0 = 0.f, s1 = 0.f;
    float m0 = -3.4e38f, m1 = -3.4e38f;
    #pragma unroll 8
    for (int it = 0; it < 32; ++it) {
        int c = wave + (it << 2);
        f32x2 v = __builtin_nontemporal_load(&xf[(long)c * (HW / 2) + (p0 >> 1) + lane]);
        tile[pa * 128 + ((c + 2 * pa) & 127)] = f2bf(v.x);
        tile[pb * 128 + ((c + 2 * pb) & 127)] = f2bf(v.y);
        s0 += v.x; s1 += v.y;
        m0 = fmaxf(m0, v.x); m1 = fmaxf(m1, v.y);
    }
    ps[wave][pa] = s0; ps[wave][pb] = s1;
    pm[wave][pa] = m0; pm[wave][pb] = m1;
    __syncthreads();

    #pragma unroll 8
    for (int it = 0; it < 32; ++it) {
        int p = wave + (it << 2);
        int colr = (2 * lane + 2 * p) & 127;          // even -> dword aligned
        unsigned int d = *reinterpret_cast<const unsigned int*>(&tile[p * 128 + colr]);
        xT[(long)(p0 + p) * 64 + lane] = d;
    }
    if (tid < 128) {
        float s = ps[0][tid] + ps[1][tid] + ps[2][tid] + ps[3][tid];
        float m = fmaxf(fmaxf(pm[0][tid], pm[1][tid]), fmaxf(pm[2][tid], pm[3][tid]));
        meanmaxP[p0 + tid] = make_float2(s * 0.0078125f, m);
    }
}

// ---------------------------------------------------------------------------
// Kernel B: fused gather + attention + depthwise. MINIMAL LDS (5.3 KB) so
// occupancy is VGPR-bound (target 8 waves/SIMD = 32/CU). Depth-2 rotating
// prefetch: 18 gather loads outstanding per wave. Output written in simple
// [l][cpair] bf16 order (kernel C transposes).
// Grid: L_TOTAL/64 = 2560 blocks, 256 threads.
// ---------------------------------------------------------------------------
__global__ __launch_bounds__(256, 8) void encoder_main_kernel(
    const unsigned int* __restrict__ xT,       // [HW][64]
    const float2* __restrict__ meanmaxP,       // [HW]
    const int* __restrict__ cks,               // [L][9]
    const float* __restrict__ att_w,           // [9][2][9]
    const float* __restrict__ att_b,           // [9]
    const float* __restrict__ depth_w,         // [128][9]
    const float* __restrict__ depth_b,         // [128]
    unsigned int* __restrict__ ybuf,           // [L][64] bf16 pairs
    float* __restrict__ gsum, float* __restrict__ gsq)
{
    __shared__ __align__(16) char smem[5312];
    float* attw = (float*)smem;                   // 162 f   [0, 648)
    float* attb = (float*)(smem + 648);           // 9 f     [648, 684) pad->688
    int*   lcks = (int*)(smem + 688);             // 576 i   [688, 2992)
    float* mult = (float*)(smem + 2992);          // 576 f   [2992, 5296)
    float* red  = (float*)smem;                   // 4096 B aliased (dead after ph2)

    const int tid = threadIdx.x;
    const int lane = tid & 63;
    const int wave = tid >> 6;
    const int c0 = lane * 2, c1 = c0 + 1;
    const int base_l = blockIdx.x * 64;

    if (tid < 162) attw[tid] = att_w[tid];
    if (tid < KS) attb[tid] = att_b[tid];
    for (int j = tid; j < 64 * KS; j += 256) lcks[j] = cks[base_l * KS + j];

    float dw0[KS], dw1[KS];
    #pragma unroll
    for (int k = 0; k < KS; ++k) {
        dw0[k] = depth_w[c0 * KS + k];
        dw1[k] = depth_w[c1 * KS + k];
    }
    const float db0 = depth_b[c0], db1 = depth_b[c1];
    __syncthreads();

    // ---- Phase 1: multipliers. thread -> (l_local = tid>>2, sub = tid&3) ----
    {
        const int l_local = tid >> 2;
        const int sub = tid & 3;
        if (sub < 3) {
            float mean[KS], mx[KS];
            #pragma unroll
            for (int k = 0; k < KS; ++k) {
                float2 mm = meanmaxP[lcks[l_local * KS + k]];
                mean[k] = mm.x; mx[k] = mm.y;
            }
            #pragma unroll
            for (int oo = 0; oo < 3; ++oo) {
                int o = sub * 3 + oo;
                float logit = attb[o];
                #pragma unroll
                for (int k = 0; k < KS; ++k) {
                    logit = fmaf(mean[k], attw[o * 18 + k], logit);
                    logit = fmaf(mx[k],   attw[o * 18 + 9 + k], logit);
                }
                mult[l_local * KS + o] = 1.0f + 1.0f / (1.0f + __expf(-logit));
            }
        }
    }
    __syncthreads();

    // ---- Phase 2: depth-2 rotating prefetch gather + depthwise ----
    float sum0 = 0.f, sum1 = 0.f, sq0 = 0.f, sq1 = 0.f;
    const int l0 = wave * LPW;

    unsigned int g[2][KS];
    #pragma unroll
    for (int k = 0; k < KS; ++k) {
        int idx = __builtin_amdgcn_readfirstlane(lcks[l0 * KS + k]);
        g[0][k] = xT[(long)idx * 64 + lane];
    }
    #pragma unroll
    for (int k = 0; k < KS; ++k) {
        int idx = __builtin_amdgcn_readfirstlane(lcks[(l0 + 1) * KS + k]);
        g[1][k] = xT[(long)idx * 64 + lane];
    }

    #pragma unroll
    for (int li = 0; li < LPW; ++li) {
        const int l_local = l0 + li;
        float acc0 = db0, acc1 = db1;
        #pragma unroll
        for (int k = 0; k < KS; ++k) {
            unsigned int p = g[li & 1][k];
            float mk = mult[l_local * KS + k];
            acc0 = fmaf(bflo(p) * mk, dw0[k], acc0);
            acc1 = fmaf(bfhi(p) * mk, dw1[k], acc1);
        }
        if (li + 2 < LPW) {
            #pragma unroll
            for (int k = 0; k < KS; ++k) {
                int idx = __builtin_amdgcn_readfirstlane(lcks[(l_local + 2) * KS + k]);
                g[li & 1][k] = xT[(long)idx * 64 + lane];
            }
        }
        __builtin_nontemporal_store(pack2(acc0, acc1),
                                    &ybuf[(long)(base_l + l_local) * 64 + lane]);
        sum0 += acc0; sum1 += acc1;
        sq0 = fmaf(acc0, acc0, sq0);
        sq1 = fmaf(acc1, acc1, sq1);
    }

    __syncthreads();                 // everything in smem dead now
    red[0 * 256 + tid] = sum0;
    red[1 * 256 + tid] = sum1;
    red[2 * 256 + tid] = sq0;
    red[3 * 256 + tid] = sq1;
    __syncthreads();

    const int grp = tid >> 6;
    const int i = tid & 63;
    float t = red[grp * 256 + i] + red[grp * 256 + 64 + i] +
              red[grp * 256 + 128 + i] + red[grp * 256 + 192 + i];
    float* dst = (grp & 2) ? gsq : gsum;
    atomicAdd(&dst[2 * i + (grp & 1)], t);
}

// ---------------------------------------------------------------------------
// Kernel C: BN finalize + SiLU + transpose ybuf[l][c] (bf16) -> out[q][c][r]
// (fp32) via LDS tile [c][r] (reads conflict-free, writes 4-way).
// Grid: Q*(M*M/128) = 1280 blocks, 256 threads.
// ---------------------------------------------------------------------------
__global__ __launch_bounds__(256) void finalize_kernel(
    const unsigned int* __restrict__ ybuf,     // [L][64]
    const float* __restrict__ gsum, const float* __restrict__ gsq,
    const float* __restrict__ gamma, const float* __restrict__ beta,
    float* __restrict__ out)                   // [Q*NCH][16384]
{
    __shared__ unsigned short tile[128 * 130];  // [c][r], stride 130
    const int tid = threadIdx.x;
    const int lane = tid & 63;
    const int wave = tid >> 6;
    const int q = blockIdx.x >> 7;
    const int r0 = (blockIdx.x & 127) * 128;
    const int c0 = 2 * lane, c1 = c0 + 1;

    const long lbase = (long)q * 16384 + r0;
    #pragma unroll 8
    for (int it = 0; it < 32; ++it) {
        int r = wave + (it << 2);
        unsigned int u = __builtin_nontemporal_load(&ybuf[(lbase + r) * 64 + lane]);
        tile[c0 * 130 + r] = (unsigned short)(u & 0xffffu);
        tile[c1 * 130 + r] = (unsigned short)(u >> 16);
    }
    __syncthreads();

    const float invN = 1.0f / (float)L_TOTAL;
    #pragma unroll 4
    for (int it = 0; it < 32; ++it) {
        int c = wave + (it << 2);
        float m = gsum[c] * invN;
        float var = gsq[c] * invN - m * m;
        float sc = gamma[c] * rsqrtf(var + 1e-5f);
        float sh = beta[c] - m * sc;
        unsigned int d = *reinterpret_cast<const unsigned int*>(&tile[c * 130 + 2 * lane]);
        float z0 = fmaf(bflo(d), sc, sh);
        float z1 = fmaf(bfhi(d), sc, sh);
        f32x2 v;
        v.x = z0 / (1.0f + __expf(-z0));
        v.y = z1 / (1.0f + __expf(-z1));
        __builtin_nontemporal_store(v,
            (f32x2*)&out[((long)(q * NCH + c) << 14) + r0 + 2 * lane]);
    }
}

extern "C" void kernel_launch(void* const* d_in, const int* in_sizes, int n_in,
                              void* d_out, int out_size, void* d_ws, size_t ws_size,
                              hipStream_t stream) {
    const f32x2* x_f2  = (const f32x2*)d_in[0];
    const int* cks     = (const int*)d_in[1];
    const float* aw    = (const float*)d_in[2];
    const float* ab    = (const float*)d_in[3];
    const float* dw    = (const float*)d_in[4];
    const float* db    = (const float*)d_in[5];
    const float* gm    = (const float*)d_in[6];
    const float* bt    = (const float*)d_in[7];

    char* ws = (char*)d_ws;
    unsigned int* xT   = (unsigned int*)ws;                  // 33,554,432 B
    float2* meanmaxP   = (float2*)(ws + 33554432);           // 1,048,576 B
    unsigned int* ybuf = (unsigned int*)(ws + 34603008);     // 41,943,040 B
    float* gsum        = (float*)(ws + 34603008 + 41943040); // 512 B
    float* gsq         = gsum + NCH;                         // 512 B

    hipMemsetAsync(gsum, 0, 2 * NCH * sizeof(float), stream);

    transpose_x_kernel<<<HW / 128, 256, 0, stream>>>(x_f2, xT, meanmaxP);
    encoder_main_kernel<<<L_TOTAL / 64, 256, 0, stream>>>(
        xT, meanmaxP, cks, aw, ab, dw, db, ybuf, gsum, gsq);
    finalize_kernel<<<1280, 256, 0, stream>>>(
        ybuf, gsum, gsq, gm, bt, (float*)d_out);
}

// Round 9
// 319.107 us; speedup vs baseline: 1.0602x; 1.0602x over previous
//
#include <hip/hip_runtime.h>
#include <hip/hip_bf16.h>

#define HW 131072      // h*w
#define NCH 128        // channels
#define KS 9
#define L_TOTAL 163840 // Q*M*M
#define LPW 16         // l's per wave in main kernel

typedef float        f32x2 __attribute__((ext_vector_type(2)));
typedef float        f32x4 __attribute__((ext_vector_type(4)));

static __device__ __forceinline__ float bflo(unsigned int p) { return __uint_as_float(p << 16); }
static __device__ __forceinline__ float bfhi(unsigned int p) { return __uint_as_float(p & 0xffff0000u); }
static __device__ __forceinline__ unsigned short f2bf(float f) {
    unsigned int x = __float_as_uint(f);
    return (unsigned short)((x + 0x7fffu + ((x >> 16) & 1u)) >> 16);  // RNE
}
static __device__ __forceinline__ unsigned int pack2(float a, float b) {
    return (unsigned int)f2bf(a) | ((unsigned int)f2bf(b) << 16);
}

// ---------------------------------------------------------------------------
// Kernel A: transpose x[c][p] (fp32) -> xT[p][c] (bf16 pairs) AND per-p
// channel mean/max. x read nt (read-once).
// Grid: HW/128 = 1024 blocks, 256 threads.
// ---------------------------------------------------------------------------
__global__ __launch_bounds__(256) void transpose_x_kernel(
    const f32x2* __restrict__ xf,         // x: [NCH][HW/2] float2 along p
    unsigned int* __restrict__ xT,        // [HW][NCH/2] uint pairs along c
    float2* __restrict__ meanmaxP)        // [HW] (mean, max) over channels
{
    __shared__ unsigned short tile[128 * 128];  // [p][col'], rotate swizzle
    __shared__ float ps[4][128];
    __shared__ float pm[4][128];
    const int tid = threadIdx.x;
    const int lane = tid & 63;
    const int wave = tid >> 6;
    const int p0 = blockIdx.x * 128;
    const int pa = 2 * lane, pb = 2 * lane + 1;

    float s0 = 0.f, s1 = 0.f;
    float m0 = -3.4e38f, m1 = -3.4e38f;
    #pragma unroll 8
    for (int it = 0; it < 32; ++it) {
        int c = wave + (it << 2);
        f32x2 v = __builtin_nontemporal_load(&xf[(long)c * (HW / 2) + (p0 >> 1) + lane]);
        tile[pa * 128 + ((c + 2 * pa) & 127)] = f2bf(v.x);
        tile[pb * 128 + ((c + 2 * pb) & 127)] = f2bf(v.y);
        s0 += v.x; s1 += v.y;
        m0 = fmaxf(m0, v.x); m1 = fmaxf(m1, v.y);
    }
    ps[wave][pa] = s0; ps[wave][pb] = s1;
    pm[wave][pa] = m0; pm[wave][pb] = m1;
    __syncthreads();

    #pragma unroll 8
    for (int it = 0; it < 32; ++it) {
        int p = wave + (it << 2);
        int colr = (2 * lane + 2 * p) & 127;          // even -> dword aligned
        unsigned int d = *reinterpret_cast<const unsigned int*>(&tile[p * 128 + colr]);
        xT[(long)(p0 + p) * 64 + lane] = d;
    }
    if (tid < 128) {
        float s = ps[0][tid] + ps[1][tid] + ps[2][tid] + ps[3][tid];
        float m = fmaxf(fmaxf(pm[0][tid], pm[1][tid]), fmaxf(pm[2][tid], pm[3][tid]));
        meanmaxP[p0 + tid] = make_float2(s * 0.0078125f, m);
    }
}

// ---------------------------------------------------------------------------
// Kernel B: fused gather + attention + depthwise.
// KEY: phase-2 address path is all scalar-side. readfirstlane(l) once per l;
// cks indices come in via s_load (uniform pointer); each gather is
// global_load_dword v, v(lane*4), s[row] — back-to-back issue, no LDS
// round-trip between loads. Multipliers read as wave-uniform ds_read_b128.
// Grid: L_TOTAL/64 = 2560 blocks, 256 threads.
// ---------------------------------------------------------------------------
__global__ __launch_bounds__(256, 6) void encoder_main_kernel(
    const unsigned int* __restrict__ xT,       // [HW][64]
    const float2* __restrict__ meanmaxP,       // [HW]
    const int* __restrict__ cks,               // [L][9]
    const float* __restrict__ att_w,           // [9][2][9]
    const float* __restrict__ att_b,           // [9]
    const float* __restrict__ depth_w,         // [128][9]
    const float* __restrict__ depth_b,         // [128]
    unsigned int* __restrict__ ybuf,           // [L][64] bf16 pairs
    float* __restrict__ gsum, float* __restrict__ gsq)
{
    __shared__ __align__(16) char smem[6080];
    float* attw   = (float*)smem;                 // 162 f  [0, 648)
    float* attb   = (float*)(smem + 648);         // 9 f    [648, 684) pad->688
    int*   lcks   = (int*)(smem + 688);           // 576 i  [688, 2992)
    float* mult12 = (float*)(smem + 2992);        // 64*12 f [2992, 6064)
    float* red    = (float*)smem;                 // 4096 B aliased (dead later)

    const int tid = threadIdx.x;
    const int lane = tid & 63;
    const int wave = tid >> 6;
    const int c0 = lane * 2, c1 = c0 + 1;
    const int base_l = blockIdx.x * 64;

    if (tid < 162) attw[tid] = att_w[tid];
    if (tid < KS) attb[tid] = att_b[tid];
    for (int j = tid; j < 64 * KS; j += 256) lcks[j] = cks[base_l * KS + j];

    float dw0[KS], dw1[KS];
    #pragma unroll
    for (int k = 0; k < KS; ++k) {
        dw0[k] = depth_w[c0 * KS + k];
        dw1[k] = depth_w[c1 * KS + k];
    }
    const float db0 = depth_b[c0], db1 = depth_b[c1];
    __syncthreads();

    // ---- Phase 1: multipliers. thread -> (l_local = tid>>2, sub = tid&3) ----
    {
        const int l_local = tid >> 2;
        const int sub = tid & 3;
        if (sub < 3) {
            float mean[KS], mx[KS];
            #pragma unroll
            for (int k = 0; k < KS; ++k) {
                float2 mm = meanmaxP[lcks[l_local * KS + k]];
                mean[k] = mm.x; mx[k] = mm.y;
            }
            #pragma unroll
            for (int oo = 0; oo < 3; ++oo) {
                int o = sub * 3 + oo;
                float logit = attb[o];
                #pragma unroll
                for (int k = 0; k < KS; ++k) {
                    logit = fmaf(mean[k], attw[o * 18 + k], logit);
                    logit = fmaf(mx[k],   attw[o * 18 + 9 + k], logit);
                }
                mult12[l_local * 12 + o] = 1.0f + 1.0f / (1.0f + __expf(-logit));
            }
        }
    }
    __syncthreads();

    // ---- Phase 2: scalar-addressed gather + depthwise ----
    float sum0 = 0.f, sum1 = 0.f, sq0 = 0.f, sq1 = 0.f;
    const int lw0 = base_l + wave * LPW;

    #pragma unroll
    for (int li = 0; li < LPW; ++li) {
        const int l = __builtin_amdgcn_readfirstlane(lw0 + li);
        const int* ckp = cks + (long)l * KS;       // uniform -> s_load
        int idx[KS];
        #pragma unroll
        for (int k = 0; k < KS; ++k) idx[k] = ckp[k];

        unsigned int pv[KS];
        #pragma unroll
        for (int k = 0; k < KS; ++k) {
            const unsigned int* rowp = xT + ((long)idx[k] << 6);  // uniform base
            pv[k] = rowp[lane];                    // saddr + v(lane*4)
        }

        const int ll = wave * LPW + li;
        f32x4 mA = *(const f32x4*)&mult12[ll * 12 + 0];
        f32x4 mB = *(const f32x4*)&mult12[ll * 12 + 4];
        float m8 = mult12[ll * 12 + 8];
        float mk[KS] = {mA.x, mA.y, mA.z, mA.w, mB.x, mB.y, mB.z, mB.w, m8};

        float acc0 = db0, acc1 = db1;
        #pragma unroll
        for (int k = 0; k < KS; ++k) {
            acc0 = fmaf(bflo(pv[k]) * mk[k], dw0[k], acc0);
            acc1 = fmaf(bfhi(pv[k]) * mk[k], dw1[k], acc1);
        }

        ybuf[(long)l * 64 + lane] = pack2(acc0, acc1);
        sum0 += acc0; sum1 += acc1;
        sq0 = fmaf(acc0, acc0, sq0);
        sq1 = fmaf(acc1, acc1, sq1);
    }

    __syncthreads();                 // smem front section dead now
    red[0 * 256 + tid] = sum0;
    red[1 * 256 + tid] = sum1;
    red[2 * 256 + tid] = sq0;
    red[3 * 256 + tid] = sq1;
    __syncthreads();

    const int grp = tid >> 6;
    const int i = tid & 63;
    float t = red[grp * 256 + i] + red[grp * 256 + 64 + i] +
              red[grp * 256 + 128 + i] + red[grp * 256 + 192 + i];
    float* dst = (grp & 2) ? gsq : gsum;
    atomicAdd(&dst[2 * i + (grp & 1)], t);
}

// ---------------------------------------------------------------------------
// Kernel C: BN finalize + SiLU + transpose ybuf[l][c] (bf16) -> out[q][c][r]
// (fp32) via LDS tile [c][r].
// Grid: Q*(M*M/128) = 1280 blocks, 256 threads.
// ---------------------------------------------------------------------------
__global__ __launch_bounds__(256) void finalize_kernel(
    const unsigned int* __restrict__ ybuf,     // [L][64]
    const float* __restrict__ gsum, const float* __restrict__ gsq,
    const float* __restrict__ gamma, const float* __restrict__ beta,
    float* __restrict__ out)                   // [Q*NCH][16384]
{
    __shared__ unsigned short tile[128 * 130];  // [c][r], stride 130
    const int tid = threadIdx.x;
    const int lane = tid & 63;
    const int wave = tid >> 6;
    const int q = blockIdx.x >> 7;
    const int r0 = (blockIdx.x & 127) * 128;
    const int c0 = 2 * lane, c1 = c0 + 1;

    const long lbase = (long)q * 16384 + r0;
    #pragma unroll 8
    for (int it = 0; it < 32; ++it) {
        int r = wave + (it << 2);
        unsigned int u = __builtin_nontemporal_load(&ybuf[(lbase + r) * 64 + lane]);
        tile[c0 * 130 + r] = (unsigned short)(u & 0xffffu);
        tile[c1 * 130 + r] = (unsigned short)(u >> 16);
    }
    __syncthreads();

    const float invN = 1.0f / (float)L_TOTAL;
    #pragma unroll 4
    for (int it = 0; it < 32; ++it) {
        int c = wave + (it << 2);
        float m = gsum[c] * invN;
        float var = gsq[c] * invN - m * m;
        float sc = gamma[c] * rsqrtf(var + 1e-5f);
        float sh = beta[c] - m * sc;
        unsigned int d = *reinterpret_cast<const unsigned int*>(&tile[c * 130 + 2 * lane]);
        float z0 = fmaf(bflo(d), sc, sh);
        float z1 = fmaf(bfhi(d), sc, sh);
        f32x2 v;
        v.x = z0 / (1.0f + __expf(-z0));
        v.y = z1 / (1.0f + __expf(-z1));
        *(f32x2*)&out[((long)(q * NCH + c) << 14) + r0 + 2 * lane] = v;
    }
}

extern "C" void kernel_launch(void* const* d_in, const int* in_sizes, int n_in,
                              void* d_out, int out_size, void* d_ws, size_t ws_size,
                              hipStream_t stream) {
    const f32x2* x_f2  = (const f32x2*)d_in[0];
    const int* cks     = (const int*)d_in[1];
    const float* aw    = (const float*)d_in[2];
    const float* ab    = (const float*)d_in[3];
    const float* dw    = (const float*)d_in[4];
    const float* db    = (const float*)d_in[5];
    const float* gm    = (const float*)d_in[6];
    const float* bt    = (const float*)d_in[7];

    char* ws = (char*)d_ws;
    unsigned int* xT   = (unsigned int*)ws;                  // 33,554,432 B
    float2* meanmaxP   = (float2*)(ws + 33554432);           // 1,048,576 B
    unsigned int* ybuf = (unsigned int*)(ws + 34603008);     // 41,943,040 B
    float* gsum        = (float*)(ws + 34603008 + 41943040); // 512 B
    float* gsq         = gsum + NCH;                         // 512 B

    hipMemsetAsync(gsum, 0, 2 * NCH * sizeof(float), stream);

    transpose_x_kernel<<<HW / 128, 256, 0, stream>>>(x_f2, xT, meanmaxP);
    encoder_main_kernel<<<L_TOTAL / 64, 256, 0, stream>>>(
        xT, meanmaxP, cks, aw, ab, dw, db, ybuf, gsum, gsq);
    finalize_kernel<<<1280, 256, 0, stream>>>(
        ybuf, gsum, gsq, gm, bt, (float*)d_out);
}